// Round 10
// baseline (149.328 us; speedup 1.0000x reference)
//
#include <hip/hip_runtime.h>
#include <math.h>

typedef __attribute__((ext_vector_type(8))) short bf16x8;
typedef __attribute__((ext_vector_type(16))) float f32x16;

constexpr int Bn = 4, Cn = 128, C8n = 16, Nn = 4096;

#if __has_builtin(__builtin_amdgcn_exp2f)
#define EXP2F(x) __builtin_amdgcn_exp2f(x)
#else
#define EXP2F(x) exp2f(x)
#endif

__device__ inline unsigned short f2bf(float f) {   // RTNE
    unsigned u = __builtin_bit_cast(unsigned, f);
    u += 0x7fff + ((u >> 16) & 1);
    return (unsigned short)(u >> 16);
}
__device__ inline unsigned pack2(float a, float b) {
    return (unsigned)f2bf(a) | ((unsigned)f2bf(b) << 16);
}
__device__ inline unsigned pkt(float a, float b) {  // truncating pack: lo=a, hi=b
#if __has_builtin(__builtin_amdgcn_perm)
    return __builtin_amdgcn_perm(__builtin_bit_cast(unsigned, b),
                                 __builtin_bit_cast(unsigned, a), 0x07060302u);
#else
    return (__builtin_bit_cast(unsigned, a) >> 16) |
           (__builtin_bit_cast(unsigned, b) & 0xffff0000u);
#endif
}

// ---------------------------------------------------------------------------
// Kernel 1: fused qkv projection GEMM (MFMA), R10:
// x-tile staged via coalesced float4 -> LDS (32 KB), A-frags from LDS reads
// (was 64 scalar global dwords/thread). m-split gridDim.y (2 blocks/CU).
//   y=0: m {0=qk, 1, 2} -> qT/kT + vsw ct0,ct1 ; y=1: m {3,4} -> ct2,ct3
// ---------------------------------------------------------------------------
__global__ __launch_bounds__(256) void qkv_kernel(
    const float* __restrict__ x,
    const float* __restrict__ Wq, const float* __restrict__ bq,
    const float* __restrict__ Wk, const float* __restrict__ bk,
    const float* __restrict__ Wv, const float* __restrict__ bv,
    unsigned short* __restrict__ qT, unsigned short* __restrict__ kT,
    unsigned short* __restrict__ vsw)
{
    __shared__ float xs[Cn][64];                 // 32 KB x-tile (fp32)
    __shared__ unsigned short wlds[96 * 128];    // 24 KB W bf16, swizzled
    __shared__ unsigned short v_s[64 * 64];      // 8 KB [64 local ch][64 n]
    __shared__ float qk_s[32][65];               // y=0 only
    __shared__ float bfl[96];

    const int tid = threadIdx.x;
    const int b = blockIdx.x >> 6, n0 = (blockIdx.x & 63) << 6;
    const int y = blockIdx.y;
    const int w = tid >> 6, lane = tid & 63, col = lane & 31, half = lane >> 5;
    const int g01 = w >> 1;
    const float L2E = 1.4426950408889634f;
    const int RBASE = y ? 96 : 0;
    const int RCNT  = y ? 64 : 96;

    // ---- stage x-tile: 2048 float4, 8/thread, fully coalesced ----
    {
        const float* xb = x + ((size_t)b * Cn) * Nn + n0;
        #pragma unroll
        for (int k = 0; k < 8; ++k) {
            int i = (k << 8) + tid;
            int c = i >> 4, f4 = i & 15;
            float4 t = *reinterpret_cast<const float4*>(&xb[(size_t)c * Nn + (f4 << 2)]);
            *reinterpret_cast<float4*>(&xs[c][f4 << 2]) = t;
        }
    }

    // ---- stage this y's W rows -> LDS (bf16, q rows scaled; XOR-swizzled) ----
    {
        unsigned* wl32 = (unsigned*)wlds;
        for (int i = tid; i < RCNT * 32; i += 256) {
            int rl = i >> 5, cq = (i & 31) << 2;
            int r = RBASE + rl;
            const float* src; float sc = 1.0f;
            if (r < 16)      { src = Wq + (size_t)r * Cn;        sc = L2E; }
            else if (r < 32) { src = Wk + (size_t)(r - 16) * Cn; }
            else             { src = Wv + (size_t)(r - 32) * Cn; }
            float4 t = *reinterpret_cast<const float4*>(&src[cq]);
            int G = cq >> 3;
            unsigned* wp = wl32 + 64 * rl + 4 * (G ^ (rl & 7)) + ((cq & 7) >> 1);
            wp[0] = pack2(t.x * sc, t.y * sc);
            wp[1] = pack2(t.z * sc, t.w * sc);
        }
        if (tid < RCNT) {
            int r = RBASE + tid;
            bfl[tid] = (r < 16) ? bq[r] * L2E
                     : (r < 32) ? bk[r - 16] : bv[r - 32];
        }
    }
    __syncthreads();                                        // barrier 1

    // ---- A-frags from LDS (conflict-free; pairs merge to ds_read2) ----
    const int nloc = ((w & 1) << 5) + col;
    bf16x8 af[8];
    #pragma unroll
    for (int s = 0; s < 8; ++s) {
        const int cb = (s << 4) + (half << 3);
        float v[8];
        #pragma unroll
        for (int j = 0; j < 8; ++j) v[j] = xs[cb + j][nloc];
        uint4 u = make_uint4(pack2(v[0], v[1]), pack2(v[2], v[3]),
                             pack2(v[4], v[5]), pack2(v[6], v[7]));
        af[s] = __builtin_bit_cast(bf16x8, u);
    }

    // ---- MFMA: local m assignment ----
    const int mlA = (y == 0) ? (g01 ? 2 : 0) : g01;
    const bool hasB = (y == 0) && (g01 == 0);
    f32x16 a0, a1;
    {
        float b0 = bfl[32 * mlA + col];
        float b1 = hasB ? bfl[32 + col] : 0.0f;
        #pragma unroll
        for (int r = 0; r < 16; ++r) { a0[r] = b0; a1[r] = b1; }
    }
    #pragma unroll
    for (int s = 0; s < 8; ++s) {
        const int off = 8 * ((2 * s + half) ^ (col & 7));
        a0 = __builtin_amdgcn_mfma_f32_32x32x16_bf16(af[s],
             *(const bf16x8*)(wlds + 128 * (32 * mlA + col) + off), a0, 0, 0, 0);
        if (hasB)
            a1 = __builtin_amdgcn_mfma_f32_32x32x16_bf16(af[s],
                 *(const bf16x8*)(wlds + 128 * (32 + col) + off), a1, 0, 0, 0);
    }

    // ---- write phase: qk -> qk_s (y=0), v -> v_s (local 64 ch) ----
    unsigned* vp32 = (unsigned*)v_s;
    #define VS_WRITE(A, C0) { \
        const int c_ = (C0) + col; \
        _Pragma("unroll") for (int g = 0; g < 4; ++g) { \
            int Gn = ((w & 1) << 2) + g; \
            unsigned* up = vp32 + 32 * c_ + 4 * (Gn ^ (c_ & 7)) + (half << 1); \
            up[0] = pack2(A[4 * g],     A[4 * g + 1]); \
            up[1] = pack2(A[4 * g + 2], A[4 * g + 3]); } }

    if (y == 0) {
        if (g01 == 0) {
            #pragma unroll
            for (int r = 0; r < 16; ++r)
                qk_s[col][((w & 1) << 5) + (r & 3) + ((r >> 2) << 3) + (half << 2)] = a0[r];
            VS_WRITE(a1, 0)          // m1 -> local ch 0-31  (global ct0)
        } else {
            VS_WRITE(a0, 32)         // m2 -> local ch 32-63 (global ct1)
        }
    } else {
        if (g01 == 0) { VS_WRITE(a0, 0)  }   // m3 -> ct2
        else          { VS_WRITE(a0, 32) }   // m4 -> ct3
    }
    #undef VS_WRITE
    __syncthreads();                                        // barrier 2

    // ---- exports ----
    if (y == 0 && tid < 128) {
        int n = tid & 63, which = tid >> 6;
        unsigned wv_[8];
        #pragma unroll
        for (int i = 0; i < 8; ++i)
            wv_[i] = pack2(qk_s[16 * which + 2 * i][n], qk_s[16 * which + 2 * i + 1][n]);
        unsigned short* dst = (which ? kT : qT) + ((size_t)b * Nn + n0 + n) * C8n;
        *reinterpret_cast<uint4*>(dst)     = make_uint4(wv_[0], wv_[1], wv_[2], wv_[3]);
        *reinterpret_cast<uint4*>(dst + 8) = make_uint4(wv_[4], wv_[5], wv_[6], wv_[7]);
    }
    {   // v fragments
        const int ctl = w & 1, c_ = (ctl << 5) + col;
        const int tb = (w >> 1) << 1;
        #pragma unroll
        for (int tt = 0; tt < 2; ++tt) {
            int t = tb + tt;
            int Gn = (t << 1) + half;
            bf16x8 fr = *(const bf16x8*)(vp32 + 32 * c_ + 4 * (Gn ^ (c_ & 7)));
            size_t o_ = ((((size_t)b * 256 + (n0 >> 4) + t) * 4 + ((y << 1) | ctl)) * 64 + lane) * 8;
            *reinterpret_cast<uint4*>(&vsw[o_]) = __builtin_bit_cast(uint4, fr);
        }
    }
}

// ---------------------------------------------------------------------------
// Kernel 2: attention. R10: 2x-unrolled K-loop with K AND V prefetched one
// full iteration ahead (ping-pong register sets, all static indices).
// ---------------------------------------------------------------------------
__global__ __launch_bounds__(512) void attn_kernel(
    const unsigned short* __restrict__ qT, const unsigned short* __restrict__ kT,
    const unsigned short* __restrict__ vsw, const float* __restrict__ x,
    const float* __restrict__ gamma_p, float* __restrict__ out)
{
    __shared__ unsigned sm_u32[8192];          // 32 KB: 2 bf16 slots / final f32
    __shared__ float ls[2][2][64];
    __shared__ float invl[64];

    const int tid = threadIdx.x, wv = tid >> 6, lane = tid & 63;
    const int col = lane & 31, half = lane >> 5;
    const int xcd = blockIdx.x & 7;
    const int b = xcd >> 1;
    const int q0 = ((((blockIdx.x >> 3) << 1) | (xcd & 1))) << 6;

    const unsigned short* qb = qT + (size_t)b * Nn * C8n;
    bf16x8 qf0 = *(const bf16x8*)&qb[(size_t)(q0 + col) * C8n + 8 * half];
    bf16x8 qf1 = *(const bf16x8*)&qb[(size_t)(q0 + 32 + col) * C8n + 8 * half];

    f32x16 accA[4], accB[4];
    #pragma unroll
    for (int ct = 0; ct < 4; ++ct) { accA[ct] = {}; accB[ct] = {}; }
    float l0 = 0.0f, l1 = 0.0f;
    const unsigned short* kb = kT + (size_t)b * Nn * C8n;
    const f32x16 z = {};

#if __has_builtin(__builtin_amdgcn_permlane32_swap)
    #define MKPF(P, O, F) { \
        unsigned lo0 = pkt(P[O], P[O + 1]), lo1 = pkt(P[O + 2], P[O + 3]); \
        unsigned hi0 = pkt(P[O + 4], P[O + 5]), hi1 = pkt(P[O + 6], P[O + 7]); \
        auto r0 = __builtin_amdgcn_permlane32_swap(lo0, hi0, false, false); \
        auto r1 = __builtin_amdgcn_permlane32_swap(lo1, hi1, false, false); \
        uint4 u_ = make_uint4(r0[0], r1[0], r0[1], r1[1]); \
        F = __builtin_bit_cast(bf16x8, u_); }
#else
    #define MKPF(P, O, F) { \
        unsigned lo0 = pkt(P[O], P[O + 1]), lo1 = pkt(P[O + 2], P[O + 3]); \
        unsigned hi0 = pkt(P[O + 4], P[O + 5]), hi1 = pkt(P[O + 6], P[O + 7]); \
        unsigned t0 = half ? lo0 : hi0, t1 = half ? lo1 : hi1; \
        unsigned r0 = (unsigned)__shfl_xor((int)t0, 32); \
        unsigned r1 = (unsigned)__shfl_xor((int)t1, 32); \
        uint4 u_ = make_uint4(half ? r0 : lo0, half ? r1 : lo1, \
                              half ? hi0 : r0, half ? hi1 : r1); \
        F = __builtin_bit_cast(bf16x8, u_); }
#endif

    // prologue: load iter 0 into the A set
    bf16x8 kfA, kfB, vxA[8], vxB[8];
    {
        kfA = *(const bf16x8*)&kb[(size_t)((wv << 9) + col) * C8n + 8 * half];
        const size_t vb0 = ((((size_t)b * 256 + (wv << 5)) * 4) * 64 + lane) * 8;
        #pragma unroll
        for (int i = 0; i < 8; ++i)
            vxA[i] = *(const bf16x8*)&vsw[vb0 + (size_t)i * 512];
    }

    // one flash iteration: prefetch (KT+1) into (KN,VN), compute with (KC,VC)
    #define ITER(KT, KC, VC, KN, VN) { \
        const int ktn = ((KT) + 1) & 15; \
        const int j0n = (wv << 9) + (ktn << 5); \
        KN = *(const bf16x8*)&kb[(size_t)(j0n + col) * C8n + 8 * half]; \
        const size_t vbn = ((((size_t)b * 256 + (j0n >> 4)) * 4) * 64 + lane) * 8; \
        _Pragma("unroll") for (int i = 0; i < 8; ++i) \
            VN[i] = *(const bf16x8*)&vsw[vbn + (size_t)i * 512]; \
        { \
            f32x16 s = __builtin_amdgcn_mfma_f32_32x32x16_bf16(KC, qf0, z, 0, 0, 0); \
            float p[16]; float ps = 0.0f; \
            _Pragma("unroll") for (int r = 0; r < 16; ++r) { p[r] = EXP2F(s[r]); ps += p[r]; } \
            l0 += ps; \
            bf16x8 pf0, pf1; \
            MKPF(p, 0, pf0) MKPF(p, 8, pf1) \
            __builtin_amdgcn_s_setprio(1); \
            _Pragma("unroll") for (int ct = 0; ct < 4; ++ct) { \
                accA[ct] = __builtin_amdgcn_mfma_f32_32x32x16_bf16(VC[ct],     pf0, accA[ct], 0, 0, 0); \
                accA[ct] = __builtin_amdgcn_mfma_f32_32x32x16_bf16(VC[4 + ct], pf1, accA[ct], 0, 0, 0); \
            } \
            __builtin_amdgcn_s_setprio(0); \
        } \
        { \
            f32x16 s = __builtin_amdgcn_mfma_f32_32x32x16_bf16(KC, qf1, z, 0, 0, 0); \
            float p[16]; float ps = 0.0f; \
            _Pragma("unroll") for (int r = 0; r < 16; ++r) { p[r] = EXP2F(s[r]); ps += p[r]; } \
            l1 += ps; \
            bf16x8 pf0, pf1; \
            MKPF(p, 0, pf0) MKPF(p, 8, pf1) \
            __builtin_amdgcn_s_setprio(1); \
            _Pragma("unroll") for (int ct = 0; ct < 4; ++ct) { \
                accB[ct] = __builtin_amdgcn_mfma_f32_32x32x16_bf16(VC[ct],     pf0, accB[ct], 0, 0, 0); \
                accB[ct] = __builtin_amdgcn_mfma_f32_32x32x16_bf16(VC[4 + ct], pf1, accB[ct], 0, 0, 0); \
            } \
            __builtin_amdgcn_s_setprio(0); \
        } }

    #pragma unroll 1
    for (int kt2 = 0; kt2 < 8; ++kt2) {
        const int kt0 = kt2 << 1;
        ITER(kt0,     kfA, vxA, kfB, vxB)
        ITER(kt0 + 1, kfB, vxB, kfA, vxA)
    }
    #undef ITER
    #undef MKPF

    l0 += __shfl_xor(l0, 32);
    l1 += __shfl_xor(l1, 32);

    // ---- 8-wave merge, bf16-packed slots ----
    #define SL_STORE(SL) { \
        ls[SL][0][lane] = l0; ls[SL][1][lane] = l1; \
        unsigned* sb = sm_u32 + (SL) * 4096; \
        _Pragma("unroll") for (int ct = 0; ct < 4; ++ct) \
        _Pragma("unroll") for (int i = 0; i < 8; ++i) { \
            sb[((ct) * 8 + i) * 64 + lane]     = pkt(accA[ct][2 * i], accA[ct][2 * i + 1]); \
            sb[((4 + ct) * 8 + i) * 64 + lane] = pkt(accB[ct][2 * i], accB[ct][2 * i + 1]); } }
    #define SL_ADD(SL) { \
        l0 += ls[SL][0][lane]; l1 += ls[SL][1][lane]; \
        unsigned* sb = sm_u32 + (SL) * 4096; \
        _Pragma("unroll") for (int ct = 0; ct < 4; ++ct) \
        _Pragma("unroll") for (int i = 0; i < 8; ++i) { \
            unsigned ua = sb[((ct) * 8 + i) * 64 + lane]; \
            accA[ct][2 * i]     += __builtin_bit_cast(float, ua << 16); \
            accA[ct][2 * i + 1] += __builtin_bit_cast(float, ua & 0xffff0000u); \
            unsigned ub = sb[((4 + ct) * 8 + i) * 64 + lane]; \
            accB[ct][2 * i]     += __builtin_bit_cast(float, ub << 16); \
            accB[ct][2 * i + 1] += __builtin_bit_cast(float, ub & 0xffff0000u); } }
    #define SL_RMW(SL) { \
        ls[SL][0][lane] += l0; ls[SL][1][lane] += l1; \
        unsigned* sb = sm_u32 + (SL) * 4096; \
        _Pragma("unroll") for (int ct = 0; ct < 4; ++ct) \
        _Pragma("unroll") for (int i = 0; i < 8; ++i) { \
            unsigned ua = sb[((ct) * 8 + i) * 64 + lane]; \
            float x0 = __builtin_bit_cast(float, ua << 16) + accA[ct][2 * i]; \
            float x1 = __builtin_bit_cast(float, ua & 0xffff0000u) + accA[ct][2 * i + 1]; \
            sb[((ct) * 8 + i) * 64 + lane] = pkt(x0, x1); \
            unsigned ub = sb[((4 + ct) * 8 + i) * 64 + lane]; \
            float y0 = __builtin_bit_cast(float, ub << 16) + accB[ct][2 * i]; \
            float y1 = __builtin_bit_cast(float, ub & 0xffff0000u) + accB[ct][2 * i + 1]; \
            sb[((4 + ct) * 8 + i) * 64 + lane] = pkt(y0, y1); } }

    if (wv == 4 || wv == 5) SL_STORE(wv - 4)
    __syncthreads();
    if (wv == 0 || wv == 1) SL_ADD(wv)
    __syncthreads();
    if (wv == 6 || wv == 7) SL_STORE(wv - 6)
    __syncthreads();
    if (wv == 2 || wv == 3) SL_RMW(wv - 2)
    __syncthreads();
    if (wv == 0 || wv == 1) SL_ADD(wv)
    __syncthreads();
    if (wv == 1) SL_STORE(0)
    __syncthreads();
    float* sf = (float*)sm_u32;
    if (wv == 0) {
        SL_ADD(0)
        #pragma unroll
        for (int ct = 0; ct < 4; ++ct)
            #pragma unroll
            for (int r = 0; r < 16; ++r) {
                sf[((ct) * 16 + r) * 64 + lane]     = accA[ct][r];
                sf[((4 + ct) * 16 + r) * 64 + lane] = accB[ct][r];
            }
        if (lane < 32) { invl[col] = 1.0f / l0; invl[32 + col] = 1.0f / l1; }
    }
    __syncthreads();
    #undef SL_STORE
    #undef SL_ADD
    #undef SL_RMW

    // ---- distributed coalesced writeback: 16 passes x 512 thr ----
    {
        const float g = gamma_p[0];
        const int n = tid & 63, ci = tid >> 6;
        const float il = invl[n];
        const int qs = n >> 5, nc = n & 31;
        #pragma unroll
        for (int p = 0; p < 16; ++p) {
            int ch = (p << 3) + ci;
            int ct = ch >> 5, chl = ch & 31;
            int h = (chl >> 2) & 1, r = (chl & 3) | ((chl >> 3) << 2);
            float val = sf[((qs * 4 + ct) * 16 + r) * 64 + nc + (h << 5)];
            size_t idx = ((size_t)(b * Cn + ch)) * Nn + q0 + n;
            out[idx] = g * (val * il) + x[idx];
        }
    }
}

// ---------------------------------------------------------------------------
extern "C" void kernel_launch(void* const* d_in, const int* in_sizes, int n_in,
                              void* d_out, int out_size, void* d_ws, size_t ws_size,
                              hipStream_t stream)
{
    const float* x     = (const float*)d_in[0];
    const float* Wq    = (const float*)d_in[1];
    const float* bq    = (const float*)d_in[2];
    const float* Wk    = (const float*)d_in[3];
    const float* bk    = (const float*)d_in[4];
    const float* Wv    = (const float*)d_in[5];
    const float* bv    = (const float*)d_in[6];
    const float* gamma = (const float*)d_in[7];
    float* out = (float*)d_out;

    unsigned short* ws16 = (unsigned short*)d_ws;
    unsigned short* qTw  = ws16;                              // 262144 u16
    unsigned short* kTw  = qTw + (size_t)Bn * Nn * C8n;       // 262144 u16
    unsigned short* vsww = kTw + (size_t)Bn * Nn * C8n;       // 2097152 u16

    qkv_kernel<<<dim3(256, 2), dim3(256), 0, stream>>>(
        x, Wq, bq, Wk, bk, Wv, bv, qTw, kTw, vsww);

    attn_kernel<<<dim3(256), dim3(512), 0, stream>>>(
        qTw, kTw, vsww, x, gamma, out);
}

// Round 11
// 107.586 us; speedup vs baseline: 1.3880x; 1.3880x over previous
//
#include <hip/hip_runtime.h>
#include <math.h>

typedef __attribute__((ext_vector_type(8))) short bf16x8;
typedef __attribute__((ext_vector_type(16))) float f32x16;

constexpr int Bn = 4, Cn = 128, C8n = 16, Nn = 4096;

#if __has_builtin(__builtin_amdgcn_exp2f)
#define EXP2F(x) __builtin_amdgcn_exp2f(x)
#else
#define EXP2F(x) exp2f(x)
#endif

__device__ inline unsigned short f2bf(float f) {   // RTNE
    unsigned u = __builtin_bit_cast(unsigned, f);
    u += 0x7fff + ((u >> 16) & 1);
    return (unsigned short)(u >> 16);
}
__device__ inline unsigned pack2(float a, float b) {
    return (unsigned)f2bf(a) | ((unsigned)f2bf(b) << 16);
}
__device__ inline unsigned pkt(float a, float b) {  // truncating pack: lo=a, hi=b
#if __has_builtin(__builtin_amdgcn_perm)
    return __builtin_amdgcn_perm(__builtin_bit_cast(unsigned, b),
                                 __builtin_bit_cast(unsigned, a), 0x07060302u);
#else
    return (__builtin_bit_cast(unsigned, a) >> 16) |
           (__builtin_bit_cast(unsigned, b) & 0xffff0000u);
#endif
}

// ---------------------------------------------------------------------------
// Kernel 1: fused qkv projection GEMM (MFMA) — R10 version (kept):
// x-tile staged via coalesced float4 -> LDS, A-frags from LDS; m-split
// gridDim.y (2 blocks/CU). y=0: m{0=qk,1,2} -> qT/kT + ct0,ct1; y=1 -> ct2,ct3.
// ---------------------------------------------------------------------------
__global__ __launch_bounds__(256) void qkv_kernel(
    const float* __restrict__ x,
    const float* __restrict__ Wq, const float* __restrict__ bq,
    const float* __restrict__ Wk, const float* __restrict__ bk,
    const float* __restrict__ Wv, const float* __restrict__ bv,
    unsigned short* __restrict__ qT, unsigned short* __restrict__ kT,
    unsigned short* __restrict__ vsw)
{
    __shared__ float xs[Cn][64];                 // 32 KB x-tile (fp32)
    __shared__ unsigned short wlds[96 * 128];    // 24 KB W bf16, swizzled
    __shared__ unsigned short v_s[64 * 64];      // 8 KB [64 local ch][64 n]
    __shared__ float qk_s[32][65];               // y=0 only
    __shared__ float bfl[96];

    const int tid = threadIdx.x;
    const int b = blockIdx.x >> 6, n0 = (blockIdx.x & 63) << 6;
    const int y = blockIdx.y;
    const int w = tid >> 6, lane = tid & 63, col = lane & 31, half = lane >> 5;
    const int g01 = w >> 1;
    const float L2E = 1.4426950408889634f;
    const int RBASE = y ? 96 : 0;
    const int RCNT  = y ? 64 : 96;

    // ---- stage x-tile: 2048 float4, 8/thread, fully coalesced ----
    {
        const float* xb = x + ((size_t)b * Cn) * Nn + n0;
        #pragma unroll
        for (int k = 0; k < 8; ++k) {
            int i = (k << 8) + tid;
            int c = i >> 4, f4 = i & 15;
            float4 t = *reinterpret_cast<const float4*>(&xb[(size_t)c * Nn + (f4 << 2)]);
            *reinterpret_cast<float4*>(&xs[c][f4 << 2]) = t;
        }
    }

    // ---- stage this y's W rows -> LDS (bf16, q rows scaled; XOR-swizzled) ----
    {
        unsigned* wl32 = (unsigned*)wlds;
        for (int i = tid; i < RCNT * 32; i += 256) {
            int rl = i >> 5, cq = (i & 31) << 2;
            int r = RBASE + rl;
            const float* src; float sc = 1.0f;
            if (r < 16)      { src = Wq + (size_t)r * Cn;        sc = L2E; }
            else if (r < 32) { src = Wk + (size_t)(r - 16) * Cn; }
            else             { src = Wv + (size_t)(r - 32) * Cn; }
            float4 t = *reinterpret_cast<const float4*>(&src[cq]);
            int G = cq >> 3;
            unsigned* wp = wl32 + 64 * rl + 4 * (G ^ (rl & 7)) + ((cq & 7) >> 1);
            wp[0] = pack2(t.x * sc, t.y * sc);
            wp[1] = pack2(t.z * sc, t.w * sc);
        }
        if (tid < RCNT) {
            int r = RBASE + tid;
            bfl[tid] = (r < 16) ? bq[r] * L2E
                     : (r < 32) ? bk[r - 16] : bv[r - 32];
        }
    }
    __syncthreads();                                        // barrier 1

    // ---- A-frags from LDS (conflict-free; pairs merge to ds_read2) ----
    const int nloc = ((w & 1) << 5) + col;
    bf16x8 af[8];
    #pragma unroll
    for (int s = 0; s < 8; ++s) {
        const int cb = (s << 4) + (half << 3);
        float v[8];
        #pragma unroll
        for (int j = 0; j < 8; ++j) v[j] = xs[cb + j][nloc];
        uint4 u = make_uint4(pack2(v[0], v[1]), pack2(v[2], v[3]),
                             pack2(v[4], v[5]), pack2(v[6], v[7]));
        af[s] = __builtin_bit_cast(bf16x8, u);
    }

    // ---- MFMA: local m assignment ----
    const int mlA = (y == 0) ? (g01 ? 2 : 0) : g01;
    const bool hasB = (y == 0) && (g01 == 0);
    f32x16 a0, a1;
    {
        float b0 = bfl[32 * mlA + col];
        float b1 = hasB ? bfl[32 + col] : 0.0f;
        #pragma unroll
        for (int r = 0; r < 16; ++r) { a0[r] = b0; a1[r] = b1; }
    }
    #pragma unroll
    for (int s = 0; s < 8; ++s) {
        const int off = 8 * ((2 * s + half) ^ (col & 7));
        a0 = __builtin_amdgcn_mfma_f32_32x32x16_bf16(af[s],
             *(const bf16x8*)(wlds + 128 * (32 * mlA + col) + off), a0, 0, 0, 0);
        if (hasB)
            a1 = __builtin_amdgcn_mfma_f32_32x32x16_bf16(af[s],
                 *(const bf16x8*)(wlds + 128 * (32 + col) + off), a1, 0, 0, 0);
    }

    // ---- write phase: qk -> qk_s (y=0), v -> v_s (local 64 ch) ----
    unsigned* vp32 = (unsigned*)v_s;
    #define VS_WRITE(A, C0) { \
        const int c_ = (C0) + col; \
        _Pragma("unroll") for (int g = 0; g < 4; ++g) { \
            int Gn = ((w & 1) << 2) + g; \
            unsigned* up = vp32 + 32 * c_ + 4 * (Gn ^ (c_ & 7)) + (half << 1); \
            up[0] = pack2(A[4 * g],     A[4 * g + 1]); \
            up[1] = pack2(A[4 * g + 2], A[4 * g + 3]); } }

    if (y == 0) {
        if (g01 == 0) {
            #pragma unroll
            for (int r = 0; r < 16; ++r)
                qk_s[col][((w & 1) << 5) + (r & 3) + ((r >> 2) << 3) + (half << 2)] = a0[r];
            VS_WRITE(a1, 0)          // m1 -> local ch 0-31  (global ct0)
        } else {
            VS_WRITE(a0, 32)         // m2 -> local ch 32-63 (global ct1)
        }
    } else {
        if (g01 == 0) { VS_WRITE(a0, 0)  }   // m3 -> ct2
        else          { VS_WRITE(a0, 32) }   // m4 -> ct3
    }
    #undef VS_WRITE
    __syncthreads();                                        // barrier 2

    // ---- exports ----
    if (y == 0 && tid < 128) {
        int n = tid & 63, which = tid >> 6;
        unsigned wv_[8];
        #pragma unroll
        for (int i = 0; i < 8; ++i)
            wv_[i] = pack2(qk_s[16 * which + 2 * i][n], qk_s[16 * which + 2 * i + 1][n]);
        unsigned short* dst = (which ? kT : qT) + ((size_t)b * Nn + n0 + n) * C8n;
        *reinterpret_cast<uint4*>(dst)     = make_uint4(wv_[0], wv_[1], wv_[2], wv_[3]);
        *reinterpret_cast<uint4*>(dst + 8) = make_uint4(wv_[4], wv_[5], wv_[6], wv_[7]);
    }
    {   // v fragments
        const int ctl = w & 1, c_ = (ctl << 5) + col;
        const int tb = (w >> 1) << 1;
        #pragma unroll
        for (int tt = 0; tt < 2; ++tt) {
            int t = tb + tt;
            int Gn = (t << 1) + half;
            bf16x8 fr = *(const bf16x8*)(vp32 + 32 * c_ + 4 * (Gn ^ (c_ & 7)));
            size_t o_ = ((((size_t)b * 256 + (n0 >> 4) + t) * 4 + ((y << 1) | ctl)) * 64 + lane) * 8;
            *reinterpret_cast<uint4*>(&vsw[o_]) = __builtin_bit_cast(uint4, fr);
        }
    }
}

// ---------------------------------------------------------------------------
// Kernel 2: attention — exact R9 structure (K-prefetch only, single V set).
// R10's V ping-pong pushed live VGPRs past the cap -> compiler chose 128 VGPR
// + ~160 MB scratch spill (WRITE_SIZE 168 MB, 74 us). Reverted.
// ---------------------------------------------------------------------------
__global__ __launch_bounds__(512) void attn_kernel(
    const unsigned short* __restrict__ qT, const unsigned short* __restrict__ kT,
    const unsigned short* __restrict__ vsw, const float* __restrict__ x,
    const float* __restrict__ gamma_p, float* __restrict__ out)
{
    __shared__ unsigned sm_u32[8192];          // 32 KB: 2 bf16 slots / final f32
    __shared__ float ls[2][2][64];
    __shared__ float invl[64];

    const int tid = threadIdx.x, wv = tid >> 6, lane = tid & 63;
    const int col = lane & 31, half = lane >> 5;
    const int xcd = blockIdx.x & 7;
    const int b = xcd >> 1;
    const int q0 = ((((blockIdx.x >> 3) << 1) | (xcd & 1))) << 6;

    const unsigned short* qb = qT + (size_t)b * Nn * C8n;
    bf16x8 qf0 = *(const bf16x8*)&qb[(size_t)(q0 + col) * C8n + 8 * half];
    bf16x8 qf1 = *(const bf16x8*)&qb[(size_t)(q0 + 32 + col) * C8n + 8 * half];

    f32x16 accA[4], accB[4];
    #pragma unroll
    for (int ct = 0; ct < 4; ++ct) { accA[ct] = {}; accB[ct] = {}; }
    float l0 = 0.0f, l1 = 0.0f;
    const unsigned short* kb = kT + (size_t)b * Nn * C8n;

#if __has_builtin(__builtin_amdgcn_permlane32_swap)
    #define MKPF(P, O, F) { \
        unsigned lo0 = pkt(P[O], P[O + 1]), lo1 = pkt(P[O + 2], P[O + 3]); \
        unsigned hi0 = pkt(P[O + 4], P[O + 5]), hi1 = pkt(P[O + 6], P[O + 7]); \
        auto r0 = __builtin_amdgcn_permlane32_swap(lo0, hi0, false, false); \
        auto r1 = __builtin_amdgcn_permlane32_swap(lo1, hi1, false, false); \
        uint4 u_ = make_uint4(r0[0], r1[0], r0[1], r1[1]); \
        F = __builtin_bit_cast(bf16x8, u_); }
#else
    #define MKPF(P, O, F) { \
        unsigned lo0 = pkt(P[O], P[O + 1]), lo1 = pkt(P[O + 2], P[O + 3]); \
        unsigned hi0 = pkt(P[O + 4], P[O + 5]), hi1 = pkt(P[O + 6], P[O + 7]); \
        unsigned t0 = half ? lo0 : hi0, t1 = half ? lo1 : hi1; \
        unsigned r0 = (unsigned)__shfl_xor((int)t0, 32); \
        unsigned r1 = (unsigned)__shfl_xor((int)t1, 32); \
        uint4 u_ = make_uint4(half ? r0 : lo0, half ? r1 : lo1, \
                              half ? hi0 : r0, half ? hi1 : r1); \
        F = __builtin_bit_cast(bf16x8, u_); }
#endif

    bf16x8 kf = *(const bf16x8*)&kb[(size_t)((wv << 9) + col) * C8n + 8 * half];

    #pragma unroll 1
    for (int kt = 0; kt < 16; ++kt) {
        const int j0 = (wv << 9) + (kt << 5);
        const int j0n = (wv << 9) + (((kt + 1) & 15) << 5);
        bf16x8 kf_next = *(const bf16x8*)&kb[(size_t)(j0n + col) * C8n + 8 * half];
        const size_t vbase = ((((size_t)b * 256 + (j0 >> 4)) * 4) * 64 + lane) * 8;
        bf16x8 va[4], vb2[4];
        #pragma unroll
        for (int ct = 0; ct < 4; ++ct) {
            va[ct]  = *(const bf16x8*)&vsw[vbase + (size_t)ct * 512];
            vb2[ct] = *(const bf16x8*)&vsw[vbase + (size_t)(4 + ct) * 512];
        }
        f32x16 z = {};

        // ---- q-sub A ----
        {
            f32x16 s = __builtin_amdgcn_mfma_f32_32x32x16_bf16(kf, qf0, z, 0, 0, 0);
            float p[16]; float ps = 0.0f;
            #pragma unroll
            for (int r = 0; r < 16; ++r) { p[r] = EXP2F(s[r]); ps += p[r]; }
            l0 += ps;
            bf16x8 pf0, pf1;
            MKPF(p, 0, pf0) MKPF(p, 8, pf1)
            __builtin_amdgcn_s_setprio(1);
            #pragma unroll
            for (int ct = 0; ct < 4; ++ct) {
                accA[ct] = __builtin_amdgcn_mfma_f32_32x32x16_bf16(va[ct],  pf0, accA[ct], 0, 0, 0);
                accA[ct] = __builtin_amdgcn_mfma_f32_32x32x16_bf16(vb2[ct], pf1, accA[ct], 0, 0, 0);
            }
            __builtin_amdgcn_s_setprio(0);
        }
        // ---- q-sub B ----
        {
            f32x16 s = __builtin_amdgcn_mfma_f32_32x32x16_bf16(kf, qf1, z, 0, 0, 0);
            float p[16]; float ps = 0.0f;
            #pragma unroll
            for (int r = 0; r < 16; ++r) { p[r] = EXP2F(s[r]); ps += p[r]; }
            l1 += ps;
            bf16x8 pf0, pf1;
            MKPF(p, 0, pf0) MKPF(p, 8, pf1)
            __builtin_amdgcn_s_setprio(1);
            #pragma unroll
            for (int ct = 0; ct < 4; ++ct) {
                accB[ct] = __builtin_amdgcn_mfma_f32_32x32x16_bf16(va[ct],  pf0, accB[ct], 0, 0, 0);
                accB[ct] = __builtin_amdgcn_mfma_f32_32x32x16_bf16(vb2[ct], pf1, accB[ct], 0, 0, 0);
            }
            __builtin_amdgcn_s_setprio(0);
        }
        kf = kf_next;
    }
    #undef MKPF

    l0 += __shfl_xor(l0, 32);
    l1 += __shfl_xor(l1, 32);

    // ---- 8-wave merge, bf16-packed slots ----
    #define SL_STORE(SL) { \
        ls[SL][0][lane] = l0; ls[SL][1][lane] = l1; \
        unsigned* sb = sm_u32 + (SL) * 4096; \
        _Pragma("unroll") for (int ct = 0; ct < 4; ++ct) \
        _Pragma("unroll") for (int i = 0; i < 8; ++i) { \
            sb[((ct) * 8 + i) * 64 + lane]     = pkt(accA[ct][2 * i], accA[ct][2 * i + 1]); \
            sb[((4 + ct) * 8 + i) * 64 + lane] = pkt(accB[ct][2 * i], accB[ct][2 * i + 1]); } }
    #define SL_ADD(SL) { \
        l0 += ls[SL][0][lane]; l1 += ls[SL][1][lane]; \
        unsigned* sb = sm_u32 + (SL) * 4096; \
        _Pragma("unroll") for (int ct = 0; ct < 4; ++ct) \
        _Pragma("unroll") for (int i = 0; i < 8; ++i) { \
            unsigned ua = sb[((ct) * 8 + i) * 64 + lane]; \
            accA[ct][2 * i]     += __builtin_bit_cast(float, ua << 16); \
            accA[ct][2 * i + 1] += __builtin_bit_cast(float, ua & 0xffff0000u); \
            unsigned ub = sb[((4 + ct) * 8 + i) * 64 + lane]; \
            accB[ct][2 * i]     += __builtin_bit_cast(float, ub << 16); \
            accB[ct][2 * i + 1] += __builtin_bit_cast(float, ub & 0xffff0000u); } }
    #define SL_RMW(SL) { \
        ls[SL][0][lane] += l0; ls[SL][1][lane] += l1; \
        unsigned* sb = sm_u32 + (SL) * 4096; \
        _Pragma("unroll") for (int ct = 0; ct < 4; ++ct) \
        _Pragma("unroll") for (int i = 0; i < 8; ++i) { \
            unsigned ua = sb[((ct) * 8 + i) * 64 + lane]; \
            float x0 = __builtin_bit_cast(float, ua << 16) + accA[ct][2 * i]; \
            float x1 = __builtin_bit_cast(float, ua & 0xffff0000u) + accA[ct][2 * i + 1]; \
            sb[((ct) * 8 + i) * 64 + lane] = pkt(x0, x1); \
            unsigned ub = sb[((4 + ct) * 8 + i) * 64 + lane]; \
            float y0 = __builtin_bit_cast(float, ub << 16) + accB[ct][2 * i]; \
            float y1 = __builtin_bit_cast(float, ub & 0xffff0000u) + accB[ct][2 * i + 1]; \
            sb[((4 + ct) * 8 + i) * 64 + lane] = pkt(y0, y1); } }

    if (wv == 4 || wv == 5) SL_STORE(wv - 4)
    __syncthreads();
    if (wv == 0 || wv == 1) SL_ADD(wv)
    __syncthreads();
    if (wv == 6 || wv == 7) SL_STORE(wv - 6)
    __syncthreads();
    if (wv == 2 || wv == 3) SL_RMW(wv - 2)
    __syncthreads();
    if (wv == 0 || wv == 1) SL_ADD(wv)
    __syncthreads();
    if (wv == 1) SL_STORE(0)
    __syncthreads();
    float* sf = (float*)sm_u32;
    if (wv == 0) {
        SL_ADD(0)
        #pragma unroll
        for (int ct = 0; ct < 4; ++ct)
            #pragma unroll
            for (int r = 0; r < 16; ++r) {
                sf[((ct) * 16 + r) * 64 + lane]     = accA[ct][r];
                sf[((4 + ct) * 16 + r) * 64 + lane] = accB[ct][r];
            }
        if (lane < 32) { invl[col] = 1.0f / l0; invl[32 + col] = 1.0f / l1; }
    }
    __syncthreads();
    #undef SL_STORE
    #undef SL_ADD
    #undef SL_RMW

    // ---- distributed coalesced writeback: 16 passes x 512 thr ----
    {
        const float g = gamma_p[0];
        const int n = tid & 63, ci = tid >> 6;
        const float il = invl[n];
        const int qs = n >> 5, nc = n & 31;
        #pragma unroll
        for (int p = 0; p < 16; ++p) {
            int ch = (p << 3) + ci;
            int ct = ch >> 5, chl = ch & 31;
            int h = (chl >> 2) & 1, r = (chl & 3) | ((chl >> 3) << 2);
            float val = sf[((qs * 4 + ct) * 16 + r) * 64 + nc + (h << 5)];
            size_t idx = ((size_t)(b * Cn + ch)) * Nn + q0 + n;
            out[idx] = g * (val * il) + x[idx];
        }
    }
}

// ---------------------------------------------------------------------------
extern "C" void kernel_launch(void* const* d_in, const int* in_sizes, int n_in,
                              void* d_out, int out_size, void* d_ws, size_t ws_size,
                              hipStream_t stream)
{
    const float* x     = (const float*)d_in[0];
    const float* Wq    = (const float*)d_in[1];
    const float* bq    = (const float*)d_in[2];
    const float* Wk    = (const float*)d_in[3];
    const float* bk    = (const float*)d_in[4];
    const float* Wv    = (const float*)d_in[5];
    const float* bv    = (const float*)d_in[6];
    const float* gamma = (const float*)d_in[7];
    float* out = (float*)d_out;

    unsigned short* ws16 = (unsigned short*)d_ws;
    unsigned short* qTw  = ws16;                              // 262144 u16
    unsigned short* kTw  = qTw + (size_t)Bn * Nn * C8n;       // 262144 u16
    unsigned short* vsww = kTw + (size_t)Bn * Nn * C8n;       // 2097152 u16

    qkv_kernel<<<dim3(256, 2), dim3(256), 0, stream>>>(
        x, Wq, bq, Wk, bk, Wv, bv, qTw, kTw, vsww);

    attn_kernel<<<dim3(256), dim3(512), 0, stream>>>(
        qTw, kTw, vsww, x, gamma, out);
}